// Round 9
// baseline (211.254 us; speedup 1.0000x reference)
//
#include <hip/hip_runtime.h>
#include <hip/hip_bf16.h>
#include <stdint.h>

typedef unsigned short u16;
typedef unsigned int u32;

typedef __attribute__((ext_vector_type(8))) __bf16 bf16x8;
typedef __attribute__((ext_vector_type(4))) float f32x4;
typedef __attribute__((ext_vector_type(8))) u16 u16x8;

#define DIM 1024
#define SEQ 4096
#define NTOK 8192   // b*n
#define NBH 16      // b*h
#define NSLOT 136   // per-head split-K slots over 64-row q-tiles, balanced <=20-tile chunks
                    // nch(qt) = ceil((qt+1)/20): qt 0..19 ->1, 20..39 ->2, 40..59 ->3, 60..63 ->4

static __device__ __forceinline__ float bf2f(u16 u) {
    union { u32 u; float f; } c; c.u = ((u32)u) << 16; return c.f;
}
static __device__ __forceinline__ u16 f2bf(float f) {
    union { float f; u32 u; } c; c.f = f;
    u32 u = c.u;
    return (u16)((u + 0x7FFF + ((u >> 16) & 1)) >> 16);
}
static __device__ __forceinline__ u16 cvt_bf16(float f) {
    union { __bf16 b; u16 u; } c; c.b = (__bf16)f;  // RNE
    return c.u;
}
static __device__ __forceinline__ u32 pack_bf16(float lo, float hi) {
    return (u32)cvt_bf16(lo) | ((u32)cvt_bf16(hi) << 16);
}
static __device__ __forceinline__ f32x4 mfma_bf16(bf16x8 a, bf16x8 b, f32x4 c) {
    return __builtin_amdgcn_mfma_f32_16x16x32_bf16(a, b, c, 0, 0, 0);
}

typedef const __attribute__((address_space(1))) unsigned int* gptr_t;
typedef __attribute__((address_space(3))) unsigned int* lptr_t;

// ---------------- fused prep: LayerNorm + both weight transposes ------------
// blockIdx < NTOK:            LN row (fp32 in, bf16 out)
// NTOK   <= blockIdx < +1536: transpose wqkv [1024][1536] -> wqkvT [1536][1024]
// else (+512):                transpose wout [512][1024]  -> woutT [1024][512]
__global__ __launch_bounds__(256) void prep_kernel(const float* __restrict__ x,
                                                   const float* __restrict__ g,
                                                   const float* __restrict__ bta,
                                                   u16* __restrict__ xn,
                                                   const float* __restrict__ wqkv,
                                                   u16* __restrict__ wqkvT,
                                                   const float* __restrict__ wout,
                                                   u16* __restrict__ woutT) {
    __shared__ float red[8];
    __shared__ float tT[32][33];
    int bid = blockIdx.x;
    int tid = threadIdx.x;

    if (bid < NTOK) {
        int row = bid;
        float4 v = ((const float4*)(x + (size_t)row * DIM))[tid];
        float f[4] = {v.x, v.y, v.z, v.w};
        float s = 0.f, s2 = 0.f;
#pragma unroll
        for (int i = 0; i < 4; i++) { s += f[i]; s2 += f[i] * f[i]; }
#pragma unroll
        for (int m = 1; m < 64; m <<= 1) { s += __shfl_xor(s, m); s2 += __shfl_xor(s2, m); }
        int w = tid >> 6;
        if ((tid & 63) == 0) { red[w * 2] = s; red[w * 2 + 1] = s2; }
        __syncthreads();
        s  = red[0] + red[2] + red[4] + red[6];
        s2 = red[1] + red[3] + red[5] + red[7];
        float mu = s * (1.f / DIM);
        float var = s2 * (1.f / DIM) - mu * mu;
        float rstd = rsqrtf(var + 1e-5f);
        u16 o[4];
#pragma unroll
        for (int i = 0; i < 4; i++) {
            int c = tid * 4 + i;
            o[i] = f2bf((f[i] - mu) * rstd * g[c] + bta[c]);
        }
        *(uint64_t*)(xn + (size_t)row * DIM + tid * 4) = *(uint64_t*)o;
        return;
    }

    int tt = bid - NTOK;
    const float* src; u16* dst; int R, C, bx, by;
    if (tt < 1536) { src = wqkv; dst = wqkvT; R = 1024; C = 1536; bx = tt % 48; by = tt / 48; }
    else { tt -= 1536; src = wout; dst = woutT; R = 512; C = 1024; bx = tt & 31; by = tt >> 5; }
    int lx = tid & 31, ly = tid >> 5;
    int c = bx * 32 + lx;
#pragma unroll
    for (int i = 0; i < 32; i += 8)
        tT[ly + i][lx] = src[(size_t)(by * 32 + ly + i) * C + c];
    __syncthreads();
    int rr = by * 32 + lx;
#pragma unroll
    for (int i = 0; i < 32; i += 8)
        dst[(size_t)(bx * 32 + ly + i) * R + rr] = f2bf(tT[lx][ly + i]);
}

// ---------------- 128x128 MFMA GEMM core (m97-style global_load_lds) -------
template <int K>
static __device__ __forceinline__ void gemm_core(const u16* __restrict__ A,
                                                 const u16* __restrict__ B,
                                                 int rowBase, int colBase,
                                                 u16* A_lds, u16* B_lds,
                                                 f32x4 acc[4][4]) {
    int tid = threadIdx.x;
    int lane = tid & 63;
    int l15 = lane & 15, q4 = lane >> 4;
    int w = tid >> 6;
    int wm = w >> 1, wn = w & 1;
#pragma unroll
    for (int mt = 0; mt < 4; mt++)
#pragma unroll
        for (int nt = 0; nt < 4; nt++) acc[mt][nt] = (f32x4){0.f, 0.f, 0.f, 0.f};

    char* Ab = (char*)A_lds;
    char* Bb = (char*)B_lds;

    for (int k0 = 0; k0 < K; k0 += 32) {
        __syncthreads();
#pragma unroll
        for (int i = 0; i < 2; i++) {
            int c = i * 256 + tid;
            int r = c >> 2;
            int piece = (c & 3) * 8;
            const u16* gA = A + (size_t)(rowBase + r) * K + k0 + piece;
            const u16* gB = B + (size_t)(colBase + r) * K + k0 + piece;
            unsigned ldsOff = (unsigned)(i * 4096 + w * 1024);  // wave-uniform
            __builtin_amdgcn_global_load_lds((gptr_t)gA, (lptr_t)(Ab + ldsOff), 16, 0, 0);
            __builtin_amdgcn_global_load_lds((gptr_t)gB, (lptr_t)(Bb + ldsOff), 16, 0, 0);
        }
        __syncthreads();
        bf16x8 a[4], b[4];
#pragma unroll
        for (int mt = 0; mt < 4; mt++)
            a[mt] = *(const bf16x8*)(A_lds + (wm * 64 + mt * 16 + l15) * 32 + q4 * 8);
#pragma unroll
        for (int nt = 0; nt < 4; nt++)
            b[nt] = *(const bf16x8*)(B_lds + (wn * 64 + nt * 16 + l15) * 32 + q4 * 8);
#pragma unroll
        for (int mt = 0; mt < 4; mt++)
#pragma unroll
            for (int nt = 0; nt < 4; nt++)
                acc[mt][nt] = mfma_bf16(a[mt], b[nt], acc[mt][nt]);
    }
}

// QKV GEMM: q gets softmax scale pre-folded; v stored transposed [bh][d][n]
__global__ __launch_bounds__(256) void gemm_qkv_kernel(const u16* __restrict__ xn,
                                                       const u16* __restrict__ wT,
                                                       u16* __restrict__ qb,
                                                       u16* __restrict__ kb,
                                                       u16* __restrict__ vbT) {
    __shared__ u16 A_lds[128 * 32];
    __shared__ u16 B_lds[128 * 32];
    f32x4 acc[4][4];
    gemm_core<1024>(xn, wT, blockIdx.x * 128, blockIdx.y * 128, A_lds, B_lds, acc);
    int lane = threadIdx.x & 63;
    int w = threadIdx.x >> 6;
    int wm = w >> 1, wn = w & 1;
    const float SC = 0.125f * 1.44269504f;  // scale * log2(e), folded into q
#pragma unroll
    for (int mt = 0; mt < 4; mt++) {
#pragma unroll
        for (int nt = 0; nt < 4; nt++) {
#pragma unroll
            for (int r = 0; r < 4; r++) {
                int m = blockIdx.x * 128 + wm * 64 + mt * 16 + (lane >> 4) * 4 + r;
                int n = blockIdx.y * 128 + wn * 64 + nt * 16 + (lane & 15);
                int piece = n >> 9;
                int c = n & 511;
                int h = c >> 6;
                int d = c & 63;
                int bi = m >> 12;
                int nn = m & 4095;
                int bh = bi * 8 + h;
                float av = acc[mt][nt][r];
                if (piece == 0)      qb[((size_t)(bh * SEQ + nn) << 6) + d] = f2bf(av * SC);
                else if (piece == 1) kb[((size_t)(bh * SEQ + nn) << 6) + d] = f2bf(av);
                else                 vbT[((size_t)(bh * 64 + d) << 12) + nn] = f2bf(av);
            }
        }
    }
}

// Out projection GEMM -> d_out fp32
__global__ __launch_bounds__(256) void gemm_out_kernel(const u16* __restrict__ aout,
                                                       const u16* __restrict__ wT,
                                                       float* __restrict__ out) {
    __shared__ u16 A_lds[128 * 32];
    __shared__ u16 B_lds[128 * 32];
    f32x4 acc[4][4];
    gemm_core<512>(aout, wT, blockIdx.x * 128, blockIdx.y * 128, A_lds, B_lds, acc);
    int lane = threadIdx.x & 63;
    int w = threadIdx.x >> 6;
    int wm = w >> 1, wn = w & 1;
#pragma unroll
    for (int mt = 0; mt < 4; mt++) {
#pragma unroll
        for (int nt = 0; nt < 4; nt++) {
#pragma unroll
            for (int r = 0; r < 4; r++) {
                int m = blockIdx.x * 128 + wm * 64 + mt * 16 + (lane >> 4) * 4 + r;
                int n = blockIdx.y * 128 + wn * 64 + nt * 16 + (lane & 15);
                out[(size_t)m * DIM + n] = acc[mt][nt][r];
            }
        }
    }
}

// ---------------- split-K causal flash attention (no-max softmax) ----------
// ROUND 9 = round-8 (66us verified; shown latency-bound: T_iter ~3000cy vs
// ~700cy pipe work, and halving LDS traffic r7->r8 changed nothing) with ONE
// change: double-buffered K/V LDS + single barrier per k-tile. Iter i writes
// tile i+1's staged regs into buf[cur^1], computes tile i from buf[cur], one
// __syncthreads, flip. All write/read hazards are separated by that barrier:
// iter i-1's reads of buf[cur^1] complete before its barrier; iter i's reads
// of buf[cur] follow iter i-1's writes to it. Halves barrier count AND each
// barrier's vmcnt/lgkmcnt drain. Next-tile global loads issue BEFORE compute
// so the end-of-iter drain finds them landed (compute >> L2 latency).
// LDS 36KB (K 2x8 + V 2x8 + P 2x2KB) -> 4-block/CU cap (measured residency
// has been ~2.5 blocks at both 20KB and 24KB, so the cap is not binding).
// Grid/slots/partials/combine identical to rounds 7-8.

__global__ __launch_bounds__(128) void attn_partial_kernel(const u16* __restrict__ qb,
                                                           const u16* __restrict__ kb,
                                                           const u16* __restrict__ vbT,
                                                           u16* __restrict__ part,
                                                           float* __restrict__ lpart) {
    __shared__ u16 K_lds[2][4096];   // [buf][64 k-rows][64 d], swizzled  16KB
    __shared__ u16 V_lds[2][4096];   // [buf][64 d-rows][64 k], swizzled  16KB
    __shared__ u16 P_lds[2][1024];   // per-wave 16x64 scratch             4KB

    // XCD-aware bijective swizzle (2176 = 8 * 272).
    int bid = blockIdx.x;
    int bs = (bid & 7) * 272 + (bid >> 3);
    int idx = NBH * NSLOT - 1 - bs;
    int bh = idx / NSLOT;
    int s  = idx - bh * NSLOT;
    int qt, ci;
    if (s < 20)       { qt = s; ci = 0; }
    else if (s < 60)  { int t = s - 20;  qt = 20 + (t >> 1); ci = t & 1; }
    else if (s < 120) { int t = s - 60;  qt = 40 + t / 3;    ci = t - (t / 3) * 3; }
    else              { int t = s - 120; qt = 60 + (t >> 2); ci = t & 3; }
    int nq = qt + 1;
    int nc = (nq + 19) / 20;
    int L  = nq / nc;
    int R  = nq - L * nc;
    int kt0 = ci * L + (ci < R ? ci : R);
    int kt1 = kt0 + L + (ci < R ? 1 : 0) - 1;

    int tid = threadIdx.x;          // 0..127
    int lane = tid & 63;
    int l15 = lane & 15, g = lane >> 4;
    int w = tid >> 6;               // 0..1
    int swz = (l15 & 7) << 3;       // read-side XOR (u16 units, 16B granules)
    int rd0 = (g * 8) ^ swz;
    int rd1 = (32 + g * 8) ^ swz;

    const u16* Kp0 = kb + (size_t)bh * SEQ * 64;
    const u16* VTp = vbT + (size_t)bh * 64 * SEQ;

    // Q fragments (B-operand) for this wave's 32 q-rows, straight from global.
    bf16x8 bQ[2][2];
#pragma unroll
    for (int qs = 0; qs < 2; qs++) {
        const u16* qp = qb + ((size_t)bh * SEQ + (size_t)qt * 64 + w * 32 + qs * 16 + l15) * 64;
        bQ[qs][0] = *(const bf16x8*)(qp + g * 8);
        bQ[qs][1] = *(const bf16x8*)(qp + 32 + g * 8);
    }

    // Staging: 512 granules (16B) per 64x64 tile, 4 per thread (128 threads).
    int wcc[4], soK[4];
    size_t soV[4];
#pragma unroll
    for (int i = 0; i < 4; i++) {
        int c = tid + 128 * i;
        int r = c >> 3, gg = c & 7;
        wcc[i] = r * 64 + ((gg ^ (r & 7)) * 8);   // swizzled LDS u16 index
        soK[i] = r * 64 + gg * 8;                  // K source offset (u16)
        soV[i] = (size_t)r * SEQ + gg * 8;         // V source offset (u16), + kt*64
    }

    // Prologue: tile kt0 -> regs -> buf0; then regs <- tile kt0+1 (clamped).
    u16x8 krA[4], vrA[4];
    {
        const u16* Kt = Kp0 + (size_t)kt0 * 4096;
#pragma unroll
        for (int i = 0; i < 4; i++) {
            krA[i] = *(const u16x8*)(Kt + soK[i]);
            vrA[i] = *(const u16x8*)(VTp + soV[i] + kt0 * 64);
        }
    }
#pragma unroll
    for (int i = 0; i < 4; i++) {
        *(u16x8*)(&K_lds[0][0] + wcc[i]) = krA[i];
        *(u16x8*)(&V_lds[0][0] + wcc[i]) = vrA[i];
    }
    {
        int ktn = (kt0 < kt1) ? kt0 + 1 : kt1;
        const u16* Ktn = Kp0 + (size_t)ktn * 4096;
#pragma unroll
        for (int i = 0; i < 4; i++) {
            krA[i] = *(const u16x8*)(Ktn + soK[i]);
            vrA[i] = *(const u16x8*)(VTp + soV[i] + ktn * 64);
        }
    }

    f32x4 Oacc[2][4];
    f32x4 l_acc[2];
#pragma unroll
    for (int qs = 0; qs < 2; qs++) {
        l_acc[qs] = (f32x4){0.f, 0.f, 0.f, 0.f};
#pragma unroll
        for (int vt = 0; vt < 4; vt++) Oacc[qs][vt] = (f32x4){0.f, 0.f, 0.f, 0.f};
    }

    const __bf16 one_bf = (__bf16)1.0f;
    bf16x8 vones = {one_bf, one_bf, one_bf, one_bf, one_bf, one_bf, one_bf, one_bf};

    u16* Pw = &P_lds[w][0];

    __syncthreads();   // buf0 (tile kt0) visible to both waves

    int cur = 0;
    for (int kt = kt0; kt <= kt1; kt++) {
        if (kt < kt1) {
            // regs hold tile kt+1: write into the other buffer (read by no one
            // until after this iteration's barrier).
#pragma unroll
            for (int i = 0; i < 4; i++) {
                *(u16x8*)(&K_lds[cur ^ 1][0] + wcc[i]) = krA[i];
                *(u16x8*)(&V_lds[cur ^ 1][0] + wcc[i]) = vrA[i];
            }
            // Issue loads for tile kt+2 (clamped): they land during compute.
            int ktn = (kt + 2 <= kt1) ? kt + 2 : kt1;
            const u16* Ktn = Kp0 + (size_t)ktn * 4096;
#pragma unroll
            for (int i = 0; i < 4; i++) {
                krA[i] = *(const u16x8*)(Ktn + soK[i]);
                vrA[i] = *(const u16x8*)(VTp + soV[i] + ktn * 64);
            }
        }

        const u16* KL = &K_lds[cur][0];
        const u16* VL = &V_lds[cur][0];

        // K fragments once, reused by both q-subtiles.
        bf16x8 ka[4][2];
#pragma unroll
        for (int nt = 0; nt < 4; nt++) {
            int row = nt * 16 + l15;
            ka[nt][0] = *(const bf16x8*)(KL + row * 64 + rd0);
            ka[nt][1] = *(const bf16x8*)(KL + row * 64 + rd1);
        }

        bf16x8 aP[2][2];
#pragma unroll
        for (int qs = 0; qs < 2; qs++) {
            // QK^T (swapped): sv[nt][r] = S[q = w*32+qs*16+l15][k = kt*64+nt*16+g*4+r]
            f32x4 sv[4];
#pragma unroll
            for (int nt = 0; nt < 4; nt++) {
                f32x4 z = (f32x4){0.f, 0.f, 0.f, 0.f};
                z = mfma_bf16(ka[nt][0], bQ[qs][0], z);
                z = mfma_bf16(ka[nt][1], bQ[qs][1], z);
                sv[nt] = z;
            }

            // exp2 (+ causal mask on the diagonal tile), packed b64 write into
            // wave-private scratch (bank-balanced under the swizzle), readback.
            if (kt != qt) {
#pragma unroll
                for (int nt = 0; nt < 4; nt++) {
                    uint2 t;
                    t.x = pack_bf16(__builtin_amdgcn_exp2f(sv[nt][0]),
                                    __builtin_amdgcn_exp2f(sv[nt][1]));
                    t.y = pack_bf16(__builtin_amdgcn_exp2f(sv[nt][2]),
                                    __builtin_amdgcn_exp2f(sv[nt][3]));
                    *(uint2*)(Pw + l15 * 64 + ((nt * 16 + g * 4) ^ swz)) = t;
                }
            } else {
                int qg = w * 32 + qs * 16 + l15;
#pragma unroll
                for (int nt = 0; nt < 4; nt++) {
                    float p[4];
#pragma unroll
                    for (int r = 0; r < 4; r++) {
                        int kg = nt * 16 + g * 4 + r;
                        p[r] = (kg <= qg) ? __builtin_amdgcn_exp2f(sv[nt][r]) : 0.f;
                    }
                    uint2 t;
                    t.x = pack_bf16(p[0], p[1]);
                    t.y = pack_bf16(p[2], p[3]);
                    *(uint2*)(Pw + l15 * 64 + ((nt * 16 + g * 4) ^ swz)) = t;
                }
            }

            // P back as A-operand: lane holds P[q = l15][kd = g*8+j].
            aP[qs][0] = *(const bf16x8*)(Pw + l15 * 64 + rd0);
            aP[qs][1] = *(const bf16x8*)(Pw + l15 * 64 + rd1);
            l_acc[qs] = mfma_bf16(aP[qs][0], vones, l_acc[qs]);   // denominator
            l_acc[qs] = mfma_bf16(aP[qs][1], vones, l_acc[qs]);
        }

        // PV: each V fragment read once, feeds both q-subtiles.
#pragma unroll
        for (int vt = 0; vt < 4; vt++) {
            int vrow = vt * 16 + l15;
            bf16x8 bV0 = *(const bf16x8*)(VL + vrow * 64 + rd0);
            bf16x8 bV1 = *(const bf16x8*)(VL + vrow * 64 + rd1);
#pragma unroll
            for (int qs = 0; qs < 2; qs++) {
                Oacc[qs][vt] = mfma_bf16(aP[qs][0], bV0, Oacc[qs][vt]);
                Oacc[qs][vt] = mfma_bf16(aP[qs][1], bV1, Oacc[qs][vt]);
            }
        }

        __syncthreads();   // single barrier: separates this iter's reads from
                           // next iter's writes (and vice versa)
        cur ^= 1;
    }

    // write partials: Onum (bf16) [slot][64q][64d] + l (fp32) [slot][64q]
    // Oacc layout: O[q = w*32 + qs*16 + g*4 + r][d = vt*16 + l15]
    u16* po = part + (size_t)idx * 4096;
#pragma unroll
    for (int qs = 0; qs < 2; qs++) {
#pragma unroll
        for (int vt = 0; vt < 4; vt++)
#pragma unroll
            for (int r = 0; r < 4; r++) {
                int q = w * 32 + qs * 16 + g * 4 + r;
                int d = vt * 16 + l15;
                po[q * 64 + d] = f2bf(Oacc[qs][vt][r]);
            }
        if (l15 == 0) {
#pragma unroll
            for (int r = 0; r < 4; r++)
                lpart[(size_t)idx * 64 + w * 32 + qs * 16 + g * 4 + r] = l_acc[qs][r];
        }
    }
}

// combine partials -> aout bf16 [8192][512]
__global__ __launch_bounds__(256) void attn_combine_kernel(const u16* __restrict__ part,
                                                           const float* __restrict__ lpart,
                                                           u16* __restrict__ aout) {
    int bid = blockIdx.x;          // 16*64 blocks, one 64-row q-tile each
    int bh = bid >> 6;
    int qt = bid & 63;
    int nc, base;
    if (qt < 20)      { nc = 1; base = qt; }
    else if (qt < 40) { nc = 2; base = 20 + (qt - 20) * 2; }
    else if (qt < 60) { nc = 3; base = 60 + (qt - 40) * 3; }
    else              { nc = 4; base = 120 + (qt - 60) * 4; }
    int sb = bh * NSLOT + base;

    int t = threadIdx.x;
    int q = t >> 2;
    int dg = (t & 3) * 16;

    float acc[16];
#pragma unroll
    for (int j = 0; j < 16; j++) acc[j] = 0.f;
    float ll = 0.f;
    for (int ci = 0; ci < nc; ci++) {
        const u16* pp = part + (size_t)(sb + ci) * 4096 + q * 64 + dg;
        u16x8 v0 = *(const u16x8*)pp;
        u16x8 v1 = *(const u16x8*)(pp + 8);
#pragma unroll
        for (int j = 0; j < 8; j++) { acc[j] += bf2f(v0[j]); acc[8 + j] += bf2f(v1[j]); }
        ll += lpart[(size_t)(sb + ci) * 64 + q];
    }
    float inv = 1.f / (ll + 1e-10f);
    int b = bh >> 3, h = bh & 7;
    size_t row = (size_t)(b * SEQ + qt * 64 + q);
    u16 o[16];
#pragma unroll
    for (int j = 0; j < 16; j++) o[j] = f2bf(acc[j] * inv);
    u16* dst = aout + row * 512 + h * 64 + dg;
    *(u16x8*)dst = *(u16x8*)o;
    *(u16x8*)(dst + 8) = *(u16x8*)(o + 8);
}

extern "C" void kernel_launch(void* const* d_in, const int* in_sizes, int n_in,
                              void* d_out, int out_size, void* d_ws, size_t ws_size,
                              hipStream_t stream) {
    const float* x    = (const float*)d_in[0];
    const float* g    = (const float*)d_in[1];
    const float* bta  = (const float*)d_in[2];
    const float* wqkv = (const float*)d_in[3];
    const float* wout = (const float*)d_in[4];
    float* out = (float*)d_out;

    char* ws = (char*)d_ws;
    size_t off = 0;
    auto alloc = [&](size_t bytes) {
        void* p = ws + off;
        off += (bytes + 255) & ~(size_t)255;
        return p;
    };
    // Footprint kept <= 46.1 MB (known-good; 76 MB overran d_ws previously).
    u16* xn    = (u16*)alloc((size_t)NTOK * DIM * 2);       // 16.78 MB; dead after gemm_qkv
    u16* wqkvT = (u16*)alloc((size_t)1536 * 1024 * 2);      //  3.15 MB; dead after gemm_qkv
    u16* woutT = (u16*)alloc((size_t)1024 * 512 * 2);       //  1.05 MB; live until gemm_out
    u16* qb    = (u16*)alloc((size_t)NBH * SEQ * 64 * 2);   //  8.39 MB; dead after attn_partial
    u16* kb    = (u16*)alloc((size_t)NBH * SEQ * 64 * 2);   //  8.39 MB
    u16* vbT   = (u16*)alloc((size_t)NBH * SEQ * 64 * 2);   //  8.39 MB
    // Aliases (lifetimes disjoint by stream order, valid on every replay --
    // prep re-writes wqkvT before gemm_qkv each replay):
    // part: 2176 slots x 8KB = 17.83 MB; lpart +0.56 MB; total 18.38 MB fits
    // the dead xn+wqkvT span (19.92 MB) and never touches woutT.
    u16* part  = xn;
    float* lpart = (float*)(xn + (size_t)NBH * NSLOT * 4096);
    u16* aout  = qb;                                        // combine writes after attn_partial reads qb

    prep_kernel<<<NTOK + 1536 + 512, 256, 0, stream>>>(x, g, bta, xn, wqkv, wqkvT, wout, woutT);
    gemm_qkv_kernel<<<dim3(64, 12), 256, 0, stream>>>(xn, wqkvT, qb, kb, vbT);
    attn_partial_kernel<<<NBH * NSLOT, 128, 0, stream>>>(qb, kb, vbT, part, lpart);
    attn_combine_kernel<<<NBH * 64, 256, 0, stream>>>(part, lpart, aout);
    gemm_out_kernel<<<dim3(64, 8), 256, 0, stream>>>(aout, woutT, out);
}